// Round 7
// baseline (135.731 us; speedup 1.0000x reference)
//
#include <hip/hip_runtime.h>
#include <hip/hip_bf16.h>

// Problem constants (fixed by reference)
#define BATCH 2
#define NPTS  8192
#define BN    (BATCH * NPTS)   // 16384
#define KNN   16
#define HEADS 4
#define HD    128              // HEADS*32
#define CIN   64
#define COUT  128
#define WCOLS 384              // [WqA1 | WkA1 | Wv] columns

using short8  = __attribute__((ext_vector_type(8))) short;
using float4v = __attribute__((ext_vector_type(4))) float;
using float2v = __attribute__((ext_vector_type(2))) float;
using uint4v  = __attribute__((ext_vector_type(4))) unsigned int;

static __device__ __forceinline__ unsigned short f2bf(float x) {
    unsigned u = __float_as_uint(x);
    u += 0x7fffu + ((u >> 16) & 1u);          // round-to-nearest-even
    return (unsigned short)(u >> 16);
}
static __device__ __forceinline__ unsigned pack2(float a, float b) {
    return (unsigned)f2bf(a) | ((unsigned)f2bf(b) << 16);
}
// one packed uint (2 adjacent bf16 channels) -> float2v {even, odd}
static __device__ __forceinline__ float2v bf2pair(unsigned u) {
    float2v r;
    r.x = __uint_as_float(u << 16);
    r.y = __uint_as_float(u & 0xffff0000u);
    return r;
}

// ---- packed fp32 VOP3P (v_pk_*_f32): 2 f32 per instruction ----
static __device__ __forceinline__ float2v pk_add(float2v a, float2v b) {
    float2v d;
    asm("v_pk_add_f32 %0, %1, %2" : "=v"(d) : "v"(a), "v"(b));
    return d;
}
static __device__ __forceinline__ float2v pk_sub(float2v a, float2v b) {
    float2v d;
    asm("v_pk_add_f32 %0, %1, %2 neg_lo:[0,1] neg_hi:[0,1]" : "=v"(d) : "v"(a), "v"(b));
    return d;
}
static __device__ __forceinline__ float2v pk_mul(float2v a, float2v b) {
    float2v d;
    asm("v_pk_mul_f32 %0, %1, %2" : "=v"(d) : "v"(a), "v"(b));
    return d;
}
static __device__ __forceinline__ float2v pk_fma(float2v a, float2v b, float2v c) {
    float2v d;
    asm("v_pk_fma_f32 %0, %1, %2, %3" : "=v"(d) : "v"(a), "v"(b), "v"(c));
    return d;
}
// broadcast src0.lo to both halves:  d = a.lo * b + c
static __device__ __forceinline__ float2v pk_fma_lo(float2v a, float2v b, float2v c) {
    float2v d;
    asm("v_pk_fma_f32 %0, %1, %2, %3 op_sel_hi:[0,1,1]" : "=v"(d) : "v"(a), "v"(b), "v"(c));
    return d;
}
// broadcast src0.hi to both halves:  d = a.hi * b + c
static __device__ __forceinline__ float2v pk_fma_hi(float2v a, float2v b, float2v c) {
    float2v d;
    asm("v_pk_fma_f32 %0, %1, %2, %3 op_sel:[1,0,0] op_sel_hi:[1,1,1]" : "=v"(d) : "v"(a), "v"(b), "v"(c));
    return d;
}
static __device__ __forceinline__ float2v sx2(float2v v, int mask) {
    float2v r;
    r.x = __shfl_xor(v.x, mask, 64);
    r.y = __shfl_xor(v.y, mask, 64);
    return r;
}
static __device__ __forceinline__ unsigned cvt_pk_bf16(float lo, float hi) {
    unsigned r;
    asm("v_cvt_pk_bf16_f32 %0, %1, %2" : "=v"(r) : "v"(lo), "v"(hi));
    return r;
}

// ---------------------------------------------------------------------------
// Kernel P: fold weights into MFMA-ready transposed bf16 operands + xyz4 pack.
// ---------------------------------------------------------------------------
__global__ void prep_kernel(const float* __restrict__ Wk,
                            const float* __restrict__ Wv,
                            const float* __restrict__ Wq,
                            const float* __restrict__ A1,
                            const float* __restrict__ b1,
                            const float* __restrict__ P2,
                            const float* __restrict__ bp2,
                            const float* __restrict__ Wout,
                            const float* __restrict__ xyzs,
                            unsigned short* __restrict__ WcatT,
                            unsigned short* __restrict__ WoutT,
                            float* __restrict__ P2A1,
                            float* __restrict__ cvec,
                            float4* __restrict__ xyz4) {
    int t = blockIdx.x * blockDim.x + threadIdx.x;
    if (t < WCOLS * CIN) {                     // WcatT: u = n*64 + kk
        int n = t >> 6, kk = t & 63;
        float val;
        if (n < 2 * HD) {
            const float* w = (n < HD ? Wq : Wk) + kk * HD;
            int jj = n & (HD - 1);
            float acc = 0.f;
            #pragma unroll 4
            for (int m = 0; m < HD; m += 4) {
                float4 wr = *(const float4*)(w + m);
                acc += wr.x * A1[(m+0)*HD + jj] + wr.y * A1[(m+1)*HD + jj]
                     + wr.z * A1[(m+2)*HD + jj] + wr.w * A1[(m+3)*HD + jj];
            }
            val = acc;
        } else {
            val = Wv[kk * HD + (n - 2 * HD)];
        }
        WcatT[t] = f2bf(val);
    } else if (t < WCOLS * CIN + COUT * HD) {  // WoutT: u = n*128 + kk
        int u = t - WCOLS * CIN;
        int n = u >> 7, kk = u & 127;
        WoutT[u] = f2bf(Wout[kk * COUT + n]);
    } else if (t < WCOLS * CIN + COUT * HD + 3 * HD) {
        int u = t - (WCOLS * CIN + COUT * HD);
        int r = u / HD, j = u % HD;
        const float* w = P2 + r * HD;
        float acc = 0.f;
        #pragma unroll 4
        for (int m = 0; m < HD; m += 4) {
            float4 wr = *(const float4*)(w + m);
            acc += wr.x * A1[(m+0)*HD + j] + wr.y * A1[(m+1)*HD + j]
                 + wr.z * A1[(m+2)*HD + j] + wr.w * A1[(m+3)*HD + j];
        }
        P2A1[u] = acc;
    } else if (t < WCOLS * CIN + COUT * HD + 3 * HD + HD) {
        int j = t - (WCOLS * CIN + COUT * HD + 3 * HD);
        float acc = b1[j];
        #pragma unroll 4
        for (int m = 0; m < HD; m += 4) {
            float4 wr = *(const float4*)(bp2 + m);
            acc += wr.x * A1[(m+0)*HD + j] + wr.y * A1[(m+1)*HD + j]
                 + wr.z * A1[(m+2)*HD + j] + wr.w * A1[(m+3)*HD + j];
        }
        cvec[j] = acc;
    } else if (t < WCOLS * CIN + COUT * HD + 3 * HD + HD + BN) {
        int u = t - (WCOLS * CIN + COUT * HD + 3 * HD + HD);
        xyz4[u] = make_float4(xyzs[u*3], xyzs[u*3+1], xyzs[u*3+2], 0.f);
    }
}

// ---------------------------------------------------------------------------
// Kernel A (MFMA): QKVb[16384][384] bf16 = bf16(F) @ Wcat (+cvec on n<128).
// Swapped mfma operands -> coalesced 8B stores (R6).
// ---------------------------------------------------------------------------
#define AK 88
__global__ __launch_bounds__(256) void qkv_kernel(const float* __restrict__ F,
                                                  const unsigned short* __restrict__ WcatT,
                                                  const float* __restrict__ cvec,
                                                  unsigned short* __restrict__ QKVb) {
    __shared__ unsigned short Af[64 * AK];     // 11.3 KB
    __shared__ unsigned short Bf[WCOLS * AK];  // 67.6 KB
    int p0 = blockIdx.x * 64;
    int t = threadIdx.x;

    // stage A: 64x64 fp32 -> bf16
    #pragma unroll
    for (int i = 0; i < 4; ++i) {
        int v = t + i * 256;
        int row = v >> 4, c4 = (v & 15) * 4;
        float4 fa = *(const float4*)(F + (p0 + row) * CIN + c4);
        uint2 u = make_uint2(pack2(fa.x, fa.y), pack2(fa.z, fa.w));
        *(uint2*)(&Af[row * AK + c4]) = u;
    }
    // stage B: 384x64 bf16
    #pragma unroll
    for (int i = 0; i < 12; ++i) {
        int v = t + i * 256;                   // uint4 index: n = v>>3, j16 = v&7
        int n = v >> 3, j16 = v & 7;
        *(uint4*)(&Bf[n * AK + j16 * 8]) = ((const uint4*)WcatT)[v];
    }
    __syncthreads();

    int w = t >> 6, l = t & 63;
    int ml = l & 15, quad = l >> 4;
    int m0 = w * 16;

    short8 a0 = *(const short8*)(&Af[(m0 + ml) * AK + quad * 8]);
    short8 a1 = *(const short8*)(&Af[(m0 + ml) * AK + 32 + quad * 8]);

    #pragma unroll
    for (int nt = 0; nt < 24; ++nt) {
        short8 b0 = *(const short8*)(&Bf[(nt * 16 + ml) * AK + quad * 8]);
        short8 b1 = *(const short8*)(&Bf[(nt * 16 + ml) * AK + 32 + quad * 8]);
        float4v acc = {0.f, 0.f, 0.f, 0.f};
        // swapped operands: lane -> C[m = ml][n = nt*16 + quad*4 + r]
        acc = __builtin_amdgcn_mfma_f32_16x16x32_bf16(b0, a0, acc, 0, 0, 0);
        acc = __builtin_amdgcn_mfma_f32_16x16x32_bf16(b1, a1, acc, 0, 0, 0);
        if (nt < 8) {   // n < 128: add cvec[n]
            float4 cv = *(const float4*)(cvec + nt * 16 + quad * 4);
            acc[0] += cv.x; acc[1] += cv.y; acc[2] += cv.z; acc[3] += cv.w;
        }
        uint2 st = make_uint2(pack2(acc[0], acc[1]), pack2(acc[2], acc[3]));
        *(uint2*)(QKVb + (size_t)(p0 + m0 + ml) * WCOLS + nt * 16 + quad * 4) = st;
    }
}

// ---------------------------------------------------------------------------
// Kernel B: wave-per-2-points attention. Two independent dependency chains
// per wave interleave (latency hiding); z-loop LDS table reads shared by
// both points; h values packed into float2v pairs consumed via VOP3P op_sel
// broadcasts (no splat arrays); V loads deferred until K regs are dead.
// Per-point algorithm identical to R5.
// ---------------------------------------------------------------------------
__global__ __launch_bounds__(256) void attn_kernel(
        const float4* __restrict__ xyz4, const int* __restrict__ kg,
        const unsigned short* __restrict__ QKVb,
        const float* __restrict__ P1, const float* __restrict__ bp1,
        const float* __restrict__ P2, const float* __restrict__ bp2,
        const float* __restrict__ P2A1,
        const float* __restrict__ A2, const float* __restrict__ b2,
        unsigned short* __restrict__ FUSEDb) {
    // channel-pair-major tables (pair pi = channels 2pi, 2pi+1)
    __shared__ float4 A2pA[64];   // {A2[2c][0],A2[2c+1][0],A2[2c][1],A2[2c+1][1]}
    __shared__ float4 A2pB[64];   // heads 2,3
    __shared__ float4 WApA[64];   // {P2A1[0][2c],P2A1[0][2c+1],P2A1[1][2c],P2A1[1][2c+1]}
    __shared__ float2 WApB[64];   // {P2A1[2][2c],P2A1[2][2c+1]}
    __shared__ float4 P2s[HD];    // (P2[0][ch], P2[1][ch], P2[2][ch], bp2[ch])
    int t = threadIdx.x;
    if (t < 64) {
        int c = t * 2;
        float4 a2l = *(const float4*)(A2 + c * 4);
        float4 a2h = *(const float4*)(A2 + (c + 1) * 4);
        A2pA[t] = make_float4(a2l.x, a2h.x, a2l.y, a2h.y);
        A2pB[t] = make_float4(a2l.z, a2h.z, a2l.w, a2h.w);
        WApA[t] = make_float4(P2A1[c], P2A1[c + 1], P2A1[HD + c], P2A1[HD + c + 1]);
        WApB[t] = make_float2(P2A1[2 * HD + c], P2A1[2 * HD + c + 1]);
    }
    if (t < HD) P2s[t] = make_float4(P2[t], P2[HD + t], P2[2 * HD + t], bp2[t]);
    __syncthreads();   // once per block; no further barriers

    int lane = t & 63;
    int pA = blockIdx.x * 8 + (t >> 6) * 2;   // even
    int pB = pA + 1;                           // same batch (pA even, 8192 even)
    int b = pA >> 13;
    int cs = lane & 15, g = lane >> 4;

    // neighbor indices (streamed once: NT)
    int qnA[4], qnB[4];
    #pragma unroll
    for (int i = 0; i < 4; ++i) {
        qnA[i] = b * NPTS + __builtin_nontemporal_load(kg + pA * KNN + i * 4 + g);
        qnB[i] = b * NPTS + __builtin_nontemporal_load(kg + pB * KNN + i * 4 + g);
    }

    // issue Q + K gathers for both points up front (V deferred)
    uint4v quA = __builtin_nontemporal_load((const uint4v*)(QKVb + (size_t)pA * WCOLS) + cs);
    uint4v quB = __builtin_nontemporal_load((const uint4v*)(QKVb + (size_t)pB * WCOLS) + cs);
    uint4v kuA[4], kuB[4];
    #pragma unroll
    for (int i = 0; i < 4; ++i) {
        kuA[i] = *(const uint4v*)(QKVb + (size_t)qnA[i] * WCOLS + HD + cs * 8);
        kuB[i] = *(const uint4v*)(QKVb + (size_t)qnB[i] * WCOLS + HD + cs * 8);
    }

    // position MLP hidden per neighbor; packed pairs for op_sel consumption
    float4 pwA = xyz4[pA], pwB = xyz4[pB];
    float2v h01A[4], h01B[4];     // {h0, h1}
    float2v h22A[2], h22B[2];     // {h2(i even), h2(i odd)}
    float h2tA[4], h2tB[4];
    #pragma unroll
    for (int i = 0; i < 4; ++i) {
        float4 qwA = xyz4[qnA[i]];
        float r0 = pwA.x - qwA.x, r1 = pwA.y - qwA.y, r2 = pwA.z - qwA.z;
        float h0 = fmaxf(r0*P1[0] + r1*P1[3] + r2*P1[6] + bp1[0], 0.f);
        float h1 = fmaxf(r0*P1[1] + r1*P1[4] + r2*P1[7] + bp1[1], 0.f);
        h2tA[i]  = fmaxf(r0*P1[2] + r1*P1[5] + r2*P1[8] + bp1[2], 0.f);
        h01A[i] = (float2v){h0, h1};
        float4 qwB = xyz4[qnB[i]];
        float s0 = pwB.x - qwB.x, s1 = pwB.y - qwB.y, s2 = pwB.z - qwB.z;
        float g0 = fmaxf(s0*P1[0] + s1*P1[3] + s2*P1[6] + bp1[0], 0.f);
        float g1 = fmaxf(s0*P1[1] + s1*P1[4] + s2*P1[7] + bp1[1], 0.f);
        h2tB[i]  = fmaxf(s0*P1[2] + s1*P1[5] + s2*P1[8] + bp1[2], 0.f);
        h01B[i] = (float2v){g0, g1};
    }
    h22A[0] = (float2v){h2tA[0], h2tA[1]}; h22A[1] = (float2v){h2tA[2], h2tA[3]};
    h22B[0] = (float2v){h2tB[0], h2tB[1]}; h22B[1] = (float2v){h2tB[2], h2tB[3]};

    // z/logit loop: table reads shared by both points
    float2v plA0[4], plA1[4], plA2[4], plA3[4];
    float2v plB0[4], plB1[4], plB2[4], plB3[4];
    #pragma unroll
    for (int i = 0; i < 4; ++i) {
        plA0[i] = (float2v){0.f, 0.f}; plA1[i] = (float2v){0.f, 0.f};
        plA2[i] = (float2v){0.f, 0.f}; plA3[i] = (float2v){0.f, 0.f};
        plB0[i] = (float2v){0.f, 0.f}; plB1[i] = (float2v){0.f, 0.f};
        plB2[i] = (float2v){0.f, 0.f}; plB3[i] = (float2v){0.f, 0.f};
    }
    #pragma unroll
    for (int jp = 0; jp < 4; ++jp) {
        int pi = cs * 4 + jp;
        float4 wa = WApA[pi];
        float2 wb = WApB[pi];
        float4 aA = A2pA[pi], aB = A2pB[pi];
        float2v wa01 = {wa.x, wa.y}, wa23 = {wa.z, wa.w}, wb01 = {wb.x, wb.y};
        float2v aA01 = {aA.x, aA.y}, aA23 = {aA.z, aA.w};
        float2v aB01 = {aB.x, aB.y}, aB23 = {aB.z, aB.w};
        float2v q2A = bf2pair(quA[jp]);
        float2v q2B = bf2pair(quB[jp]);
        #pragma unroll
        for (int i = 0; i < 4; ++i) {
            // point A
            {
                float2v k2 = bf2pair(kuA[i][jp]);
                float2v acc = pk_sub(q2A, k2);
                acc = pk_fma_lo(h01A[i], wa01, acc);               // * h0
                acc = pk_fma_hi(h01A[i], wa23, acc);               // * h1
                acc = (i & 1) ? pk_fma_hi(h22A[i >> 1], wb01, acc) // * h2
                              : pk_fma_lo(h22A[i >> 1], wb01, acc);
                float2v z2;
                z2.x = fmaxf(acc.x, 0.f);
                z2.y = fmaxf(acc.y, 0.f);
                plA0[i] = pk_fma(z2, aA01, plA0[i]);
                plA1[i] = pk_fma(z2, aA23, plA1[i]);
                plA2[i] = pk_fma(z2, aB01, plA2[i]);
                plA3[i] = pk_fma(z2, aB23, plA3[i]);
            }
            // point B
            {
                float2v k2 = bf2pair(kuB[i][jp]);
                float2v acc = pk_sub(q2B, k2);
                acc = pk_fma_lo(h01B[i], wa01, acc);
                acc = pk_fma_hi(h01B[i], wa23, acc);
                acc = (i & 1) ? pk_fma_hi(h22B[i >> 1], wb01, acc)
                              : pk_fma_lo(h22B[i >> 1], wb01, acc);
                float2v z2;
                z2.x = fmaxf(acc.x, 0.f);
                z2.y = fmaxf(acc.y, 0.f);
                plB0[i] = pk_fma(z2, aA01, plB0[i]);
                plB1[i] = pk_fma(z2, aA23, plB1[i]);
                plB2[i] = pk_fma(z2, aB01, plB2[i]);
                plB3[i] = pk_fma(z2, aB23, plB3[i]);
            }
        }
    }

    // K regs dead -> issue V gathers now (latency hides under DS chains)
    uint4v vuA[4], vuB[4];
    #pragma unroll
    for (int i = 0; i < 4; ++i) {
        vuA[i] = *(const uint4v*)(QKVb + (size_t)qnA[i] * WCOLS + 2 * HD + cs * 8);
        vuB[i] = *(const uint4v*)(QKVb + (size_t)qnB[i] * WCOLS + 2 * HD + cs * 8);
    }

    // horizontal sums
    float2v PA[4], QvA[4], PB[4], QvB[4];
    #pragma unroll
    for (int i = 0; i < 4; ++i) {
        PA[i]  = (float2v){plA0[i].x + plA0[i].y, plA1[i].x + plA1[i].y};
        QvA[i] = (float2v){plA2[i].x + plA2[i].y, plA3[i].x + plA3[i].y};
        PB[i]  = (float2v){plB0[i].x + plB0[i].y, plB1[i].x + plB1[i].y};
        QvB[i] = (float2v){plB2[i].x + plB2[i].y, plB3[i].x + plB3[i].y};
    }

    // butterfly reduce-scatter (two independent chains, interleaved)
    bool hi8 = (cs & 8) != 0;
    float2v kAA = hi8 ? PA[2]  : PA[0],  sAA = hi8 ? PA[0]  : PA[2];
    float2v kBA = hi8 ? QvA[2] : QvA[0], sBA = hi8 ? QvA[0] : QvA[2];
    float2v kCA = hi8 ? PA[3]  : PA[1],  sCA = hi8 ? PA[1]  : PA[3];
    float2v kDA = hi8 ? QvA[3] : QvA[1], sDA = hi8 ? QvA[1] : QvA[3];
    float2v kAB = hi8 ? PB[2]  : PB[0],  sAB = hi8 ? PB[0]  : PB[2];
    float2v kBB = hi8 ? QvB[2] : QvB[0], sBB = hi8 ? QvB[0] : QvB[2];
    float2v kCB = hi8 ? PB[3]  : PB[1],  sCB = hi8 ? PB[1]  : PB[3];
    float2v kDB = hi8 ? QvB[3] : QvB[1], sDB = hi8 ? QvB[1] : QvB[3];
    kAA = pk_add(kAA, sx2(sAA, 8)); kAB = pk_add(kAB, sx2(sAB, 8));
    kBA = pk_add(kBA, sx2(sBA, 8)); kBB = pk_add(kBB, sx2(sBB, 8));
    kCA = pk_add(kCA, sx2(sCA, 8)); kCB = pk_add(kCB, sx2(sCB, 8));
    kDA = pk_add(kDA, sx2(sDA, 8)); kDB = pk_add(kDB, sx2(sDB, 8));
    bool hi4 = (cs & 4) != 0;
    float2v mPA = hi4 ? kCA : kAA, sPA = hi4 ? kAA : kCA;
    float2v mQA = hi4 ? kDA : kBA, sQA = hi4 ? kBA : kDA;
    float2v mPB = hi4 ? kCB : kAB, sPB = hi4 ? kAB : kCB;
    float2v mQB = hi4 ? kDB : kBB, sQB = hi4 ? kBB : kDB;
    mPA = pk_add(mPA, sx2(sPA, 4)); mPB = pk_add(mPB, sx2(sPB, 4));
    mQA = pk_add(mQA, sx2(sQA, 4)); mQB = pk_add(mQB, sx2(sQB, 4));
    bool hi2 = (cs & 2) != 0;
    float2v mTA = hi2 ? mQA : mPA, sTA = hi2 ? mPA : mQA;
    float2v mTB = hi2 ? mQB : mPB, sTB = hi2 ? mPB : mQB;
    mTA = pk_add(mTA, sx2(sTA, 2)); mTB = pk_add(mTB, sx2(sTB, 2));
    bool hi1 = (cs & 1) != 0;
    float LmA = hi1 ? mTA.y : mTA.x, LsA = hi1 ? mTA.x : mTA.y;
    float LmB = hi1 ? mTB.y : mTB.x, LsB = hi1 ? mTB.x : mTB.y;
    float LA = LmA + __shfl_xor(LsA, 1, 64);
    float LB = LmB + __shfl_xor(LsB, 1, 64);
    // L = logit(nbr = (cs>>2)*4 + g, head = cs&3); b2 cancels in softmax

    // softmax over 16 neighbors (lane bits {2,3}=i, {4,5}=g)
    float mxA = LA, mxB = LB;
    mxA = fmaxf(mxA, __shfl_xor(mxA, 4, 64));  mxB = fmaxf(mxB, __shfl_xor(mxB, 4, 64));
    mxA = fmaxf(mxA, __shfl_xor(mxA, 8, 64));  mxB = fmaxf(mxB, __shfl_xor(mxB, 8, 64));
    mxA = fmaxf(mxA, __shfl_xor(mxA, 16, 64)); mxB = fmaxf(mxB, __shfl_xor(mxB, 16, 64));
    mxA = fmaxf(mxA, __shfl_xor(mxA, 32, 64)); mxB = fmaxf(mxB, __shfl_xor(mxB, 32, 64));
    float eA = __expf(LA - mxA), eB = __expf(LB - mxB);
    float ssA = eA, ssB = eB;
    ssA += __shfl_xor(ssA, 4, 64);  ssB += __shfl_xor(ssB, 4, 64);
    ssA += __shfl_xor(ssA, 8, 64);  ssB += __shfl_xor(ssB, 8, 64);
    ssA += __shfl_xor(ssA, 16, 64); ssB += __shfl_xor(ssB, 16, 64);
    ssA += __shfl_xor(ssA, 32, 64); ssB += __shfl_xor(ssB, 32, 64);
    float aA_ = eA / ssA, aB_ = eB / ssB;

    // hb = sum_nbr a[nbr][head] * h[nbr] for head = cs&3 (static selects)
    bool sb2 = (cs & 4) != 0, sb3 = (cs & 8) != 0;
    float h0sA = sb3 ? (sb2 ? h01A[3].x : h01A[2].x) : (sb2 ? h01A[1].x : h01A[0].x);
    float h1sA = sb3 ? (sb2 ? h01A[3].y : h01A[2].y) : (sb2 ? h01A[1].y : h01A[0].y);
    float h2sA = sb3 ? (sb2 ? h22A[1].y : h22A[1].x) : (sb2 ? h22A[0].y : h22A[0].x);
    float h0sB = sb3 ? (sb2 ? h01B[3].x : h01B[2].x) : (sb2 ? h01B[1].x : h01B[0].x);
    float h1sB = sb3 ? (sb2 ? h01B[3].y : h01B[2].y) : (sb2 ? h01B[1].y : h01B[0].y);
    float h2sB = sb3 ? (sb2 ? h22B[1].y : h22B[1].x) : (sb2 ? h22B[0].y : h22B[0].x);
    float pA0 = aA_ * h0sA, pA1 = aA_ * h1sA, pA2 = aA_ * h2sA;
    float pB0 = aB_ * h0sB, pB1 = aB_ * h1sB, pB2 = aB_ * h2sB;
    pA0 += __shfl_xor(pA0, 4, 64);  pA1 += __shfl_xor(pA1, 4, 64);  pA2 += __shfl_xor(pA2, 4, 64);
    pB0 += __shfl_xor(pB0, 4, 64);  pB1 += __shfl_xor(pB1, 4, 64);  pB2 += __shfl_xor(pB2, 4, 64);
    pA0 += __shfl_xor(pA0, 8, 64);  pA1 += __shfl_xor(pA1, 8, 64);  pA2 += __shfl_xor(pA2, 8, 64);
    pB0 += __shfl_xor(pB0, 8, 64);  pB1 += __shfl_xor(pB1, 8, 64);  pB2 += __shfl_xor(pB2, 8, 64);
    pA0 += __shfl_xor(pA0, 16, 64); pA1 += __shfl_xor(pA1, 16, 64); pA2 += __shfl_xor(pA2, 16, 64);
    pB0 += __shfl_xor(pB0, 16, 64); pB1 += __shfl_xor(pB1, 16, 64); pB2 += __shfl_xor(pB2, 16, 64);
    pA0 += __shfl_xor(pA0, 32, 64); pA1 += __shfl_xor(pA1, 32, 64); pA2 += __shfl_xor(pA2, 32, 64);
    pB0 += __shfl_xor(pB0, 32, 64); pB1 += __shfl_xor(pB1, 32, 64); pB2 += __shfl_xor(pB2, 32, 64);

    // cross-map: this lane's V channels belong to head cs>>2
    float hqA0 = __shfl(pA0, cs >> 2, 64);
    float hqA1 = __shfl(pA1, cs >> 2, 64);
    float hqA2 = __shfl(pA2, cs >> 2, 64);
    float hqB0 = __shfl(pB0, cs >> 2, 64);
    float hqB1 = __shfl(pB1, cs >> 2, 64);
    float hqB2 = __shfl(pB2, cs >> 2, 64);
    int sbase = (lane & 48) | (cs >> 2);
    float avA0 = __shfl(aA_, sbase | (0 << 2), 64);
    float avA1 = __shfl(aA_, sbase | (1 << 2), 64);
    float avA2 = __shfl(aA_, sbase | (2 << 2), 64);
    float avA3 = __shfl(aA_, sbase | (3 << 2), 64);
    float avB0 = __shfl(aB_, sbase | (0 << 2), 64);
    float avB1 = __shfl(aB_, sbase | (1 << 2), 64);
    float avB2 = __shfl(aB_, sbase | (2 << 2), 64);
    float avB3 = __shfl(aB_, sbase | (3 << 2), 64);

    // V weighted accumulate, then g-reduce (both points)
    float2v apA0 = {avA0, avA0}, apA1 = {avA1, avA1}, apA2 = {avA2, avA2}, apA3 = {avA3, avA3};
    float2v apB0 = {avB0, avB0}, apB1 = {avB1, avB1}, apB2 = {avB2, avB2}, apB3 = {avB3, avB3};
    float2v wvA[4], wvB[4];
    #pragma unroll
    for (int jp = 0; jp < 4; ++jp) {
        float2v acc = pk_mul(apA0, bf2pair(vuA[0][jp]));
        acc = pk_fma(apA1, bf2pair(vuA[1][jp]), acc);
        acc = pk_fma(apA2, bf2pair(vuA[2][jp]), acc);
        acc = pk_fma(apA3, bf2pair(vuA[3][jp]), acc);
        wvA[jp] = acc;
        float2v accb = pk_mul(apB0, bf2pair(vuB[0][jp]));
        accb = pk_fma(apB1, bf2pair(vuB[1][jp]), accb);
        accb = pk_fma(apB2, bf2pair(vuB[2][jp]), accb);
        accb = pk_fma(apB3, bf2pair(vuB[3][jp]), accb);
        wvB[jp] = accb;
    }
    #pragma unroll
    for (int jp = 0; jp < 4; ++jp) {
        wvA[jp] = pk_add(wvA[jp], sx2(wvA[jp], 16));
        wvB[jp] = pk_add(wvB[jp], sx2(wvB[jp], 16));
        wvA[jp] = pk_add(wvA[jp], sx2(wvA[jp], 32));
        wvB[jp] = pk_add(wvB[jp], sx2(wvB[jp], 32));
    }

    // epilogue: fused = wv + hq @ P2 + bp2 ; write 16B/lane, g==0 lanes
    unsigned fwA[4], fwB[4];
    #pragma unroll
    for (int jp = 0; jp < 4; ++jp) {
        int ch0 = cs * 8 + 2 * jp;
        float4 pAv = P2s[ch0], pBv = P2s[ch0 + 1];
        float floA = wvA[jp].x + hqA0 * pAv.x + hqA1 * pAv.y + hqA2 * pAv.z + pAv.w;
        float fhiA = wvA[jp].y + hqA0 * pBv.x + hqA1 * pBv.y + hqA2 * pBv.z + pBv.w;
        fwA[jp] = cvt_pk_bf16(floA, fhiA);
        float floB = wvB[jp].x + hqB0 * pAv.x + hqB1 * pAv.y + hqB2 * pAv.z + pAv.w;
        float fhiB = wvB[jp].y + hqB0 * pBv.x + hqB1 * pBv.y + hqB2 * pBv.z + pBv.w;
        fwB[jp] = cvt_pk_bf16(floB, fhiB);
    }
    if (g == 0) {
        uint4v fuA = {fwA[0], fwA[1], fwA[2], fwA[3]};
        *(uint4v*)(FUSEDb + (size_t)pA * HD + cs * 8) = fuA;
        uint4v fuB = {fwB[0], fwB[1], fwB[2], fwB[3]};
        *(uint4v*)(FUSEDb + (size_t)pB * HD + cs * 8) = fuB;
    }
}

// ---------------------------------------------------------------------------
// Kernel C (MFMA): out[16384][128] = FUSEDb @ Wout + bout (fp32 out).
// ---------------------------------------------------------------------------
#define OK2 144
__global__ __launch_bounds__(256) void out_kernel(const unsigned short* __restrict__ FUSEDb,
                                                  const unsigned short* __restrict__ WoutT,
                                                  const float* __restrict__ bout,
                                                  float* __restrict__ out) {
    __shared__ unsigned short Af[64 * OK2];    // 18.4 KB
    __shared__ unsigned short Bf[HD * OK2];    // 36.9 KB
    int p0 = blockIdx.x * 64;
    int t = threadIdx.x;

    #pragma unroll
    for (int i = 0; i < 4; ++i) {              // stage A: 64 x 128 bf16
        int v = t + i * 256;
        int row = v >> 4, j16 = v & 15;
        *(uint4*)(&Af[row * OK2 + j16 * 8]) = ((const uint4*)FUSEDb)[(p0 + row) * 16 + j16];
    }
    #pragma unroll
    for (int i = 0; i < 8; ++i) {              // stage B: 128 x 128 bf16
        int v = t + i * 256;
        int n = v >> 4, j16 = v & 15;
        *(uint4*)(&Bf[n * OK2 + j16 * 8]) = ((const uint4*)WoutT)[v];
    }
    __syncthreads();

    int w = t >> 6, l = t & 63;
    int ml = l & 15, quad = l >> 4;
    int m0 = w * 16;

    short8 af[4];
    #pragma unroll
    for (int ks = 0; ks < 4; ++ks)
        af[ks] = *(const short8*)(&Af[(m0 + ml) * OK2 + ks * 32 + quad * 8]);

    #pragma unroll
    for (int nt = 0; nt < 8; ++nt) {
        float4v acc = {0.f, 0.f, 0.f, 0.f};
        #pragma unroll
        for (int ks = 0; ks < 4; ++ks) {
            short8 bf = *(const short8*)(&Bf[(nt * 16 + ml) * OK2 + ks * 32 + quad * 8]);
            // swapped operands: lane -> C[m = ml][n = nt*16 + quad*4 + r]
            acc = __builtin_amdgcn_mfma_f32_16x16x32_bf16(bf, af[ks], acc, 0, 0, 0);
        }
        float4 bo = *(const float4*)(bout + nt * 16 + quad * 4);
        float4 st = make_float4(acc[0] + bo.x, acc[1] + bo.y,
                                acc[2] + bo.z, acc[3] + bo.w);
        *(float4*)(out + (size_t)(p0 + m0 + ml) * COUT + nt * 16 + quad * 4) = st;
    }
}

// ---------------------------------------------------------------------------
extern "C" void kernel_launch(void* const* d_in, const int* in_sizes, int n_in,
                              void* d_out, int out_size, void* d_ws, size_t ws_size,
                              hipStream_t stream) {
    const float* xyzs = (const float*)d_in[0];
    const float* feat = (const float*)d_in[1];
    const int*   kg   = (const int*)  d_in[2];
    const float* Wk   = (const float*)d_in[3];
    const float* Wv   = (const float*)d_in[4];
    const float* Wq   = (const float*)d_in[5];
    const float* A1   = (const float*)d_in[6];
    const float* b1   = (const float*)d_in[7];
    const float* A2   = (const float*)d_in[8];
    const float* b2   = (const float*)d_in[9];
    const float* P1   = (const float*)d_in[10];
    const float* bp1  = (const float*)d_in[11];
    const float* P2   = (const float*)d_in[12];
    const float* bp2  = (const float*)d_in[13];
    const float* Wout = (const float*)d_in[14];
    const float* bout = (const float*)d_in[15];
    float* out = (float*)d_out;

    float* ws = (float*)d_ws;
    float* cvec = ws;                               // 128 fp32
    float* P2A1 = ws + 128;                         // 384 fp32  (total 512 fp32 = 2048 B)
    unsigned short* QKVb  = (unsigned short*)(ws + 512);         // BN*384 bf16 (12.6 MB)
    unsigned short* FUSEDb = QKVb + (size_t)BN * WCOLS;          // BN*128 bf16 (4 MB)
    unsigned short* WcatT = FUSEDb + (size_t)BN * HD;            // 384*64 bf16
    unsigned short* WoutT = WcatT + WCOLS * CIN;                 // 128*128 bf16
    float4* xyz4 = (float4*)(WoutT + COUT * HD);                 // BN float4 (256 KB)

    int prep_elems = WCOLS*CIN + COUT*HD + 3*HD + HD + BN;  // 57856
    prep_kernel<<<(prep_elems + 255) / 256, 256, 0, stream>>>(
        Wk, Wv, Wq, A1, b1, P2, bp2, Wout, xyzs, WcatT, WoutT, P2A1, cvec, xyz4);

    qkv_kernel<<<BN / 64, 256, 0, stream>>>(feat, WcatT, cvec, QKVb);

    attn_kernel<<<BN / 8, 256, 0, stream>>>(
        xyz4, kg, QKVb, P1, bp1, P2, bp2, P2A1, A2, b2, FUSEDb);

    out_kernel<<<BN / 64, 256, 0, stream>>>(FUSEDb, WoutT, bout, out);
}